// Round 17
// baseline (41.437 us; speedup 1.0000x reference)
//
#include <hip/hip_runtime.h>

#define BATCH 32
#define SS 1024
#define NSTEPS 972
#define LSTR 20                     // floats per lane row: 16 data + 4 pad = 80B (16B-aligned, 8-way bank spread)

#define UNVIS   0x7F000000u         // huge finite float sentinels: UNVIS < CLOSED < OBST, all > any real f
#define CLOSEDB 0x7F000001u
#define OBSTB   0x7F000002u

typedef unsigned long long ull;

template <int CTRL>
__device__ __forceinline__ int dpp32(int v) {
    return __builtin_amdgcn_update_dpp(v, v, CTRL, 0xF, 0xF, false);
}

// 64-lane f32 min, result (bit-exact copy of some input) broadcast via readlane(63).
__device__ __forceinline__ float wave_min_f32_bcast(float v) {
    float t;
    t = __int_as_float(dpp32<0xB1 >(__float_as_int(v))); v = fminf(v, t);  // quad xor1
    t = __int_as_float(dpp32<0x4E >(__float_as_int(v))); v = fminf(v, t);  // quad xor2
    t = __int_as_float(dpp32<0x141>(__float_as_int(v))); v = fminf(v, t);  // row_half_mirror
    t = __int_as_float(dpp32<0x140>(__float_as_int(v))); v = fminf(v, t);  // row_mirror
    t = __int_as_float(dpp32<0x142>(__float_as_int(v))); v = fminf(v, t);  // row_bcast15
    t = __int_as_float(dpp32<0x143>(__float_as_int(v))); v = fminf(v, t);  // row_bcast31
    return __int_as_float(__builtin_amdgcn_readlane(__float_as_int(v), 63));
}

__device__ __forceinline__ unsigned umin2(unsigned a, unsigned b) { return a < b ? a : b; }
__device__ __forceinline__ float fmin3(float a, float b, float c) { return fminf(fminf(a, b), c); }
__device__ __forceinline__ unsigned umin3(unsigned a, unsigned b, unsigned c) { return umin2(umin2(a, b), c); }
__device__ __forceinline__ unsigned slotc(float v, unsigned lm, unsigned i) {
    return (__float_as_uint(v) == lm) ? i : 63u;   // lane-local slot candidate
}

__global__ __launch_bounds__(64)
void astar_kernel(const float* __restrict__ start_maps,
                  const float* __restrict__ goal_maps,
                  const float* __restrict__ obst_maps,
                  float* __restrict__ out)
{
    const int b = blockIdx.x;
    const int lane = threadIdx.x;

    __shared__ __align__(16) float fop[64 * LSTR];   // padded: cell c at (c>>4)*LSTR + (c&15)
    __shared__ __align__(16) float g_s[SS];
    __shared__ unsigned short par_s[SS];
    __shared__ int sh_start, sh_goal;

    const float* st = start_maps + b * SS;
    const float* gl = goal_maps + b * SS;
    const float* ob = obst_maps + b * SS;

    for (int i = 0; i < 16; ++i) {
        int c = i * 64 + lane;
        if (st[c] > 0.5f) sh_start = c;
        if (gl[c] > 0.5f) sh_goal = c;
    }
    __syncthreads();
    const int start_idx = sh_start;
    const int goal_idx = sh_goal;
    const float gi = (float)(goal_idx >> 5);
    const float gj = (float)(goal_idx & 31);
    const float SQRT2F = 1.41421356237309515f;   // fl32(sqrt(2))
    const float WH = 0.501f;
    const float INFF = __int_as_float(0x7f800000);
    const float CB = __uint_as_float(CLOSEDB);

    for (int i = 0; i < 16; ++i) {
        int c = i * 64 + lane;
        g_s[c] = 0.0f;
        par_s[c] = (unsigned short)goal_idx;
        fop[(c >> 4) * LSTR + (c & 15)] = __uint_as_float(ob[c] > 0.5f ? UNVIS : OBSTB);
    }
    __syncthreads();
    if (lane == 0) {
        // f(start) = fl(0.5*0 + fl(0.501*h)) = fh, computed with reference-identical op order
        float dx0 = fabsf((float)(start_idx >> 5) - gi);
        float dy0 = fabsf((float)(start_idx & 31) - gj);
        float h0 = __fadd_rn(__fmul_rn(fminf(dx0, dy0), SQRT2F), fabsf(dx0 - dy0));
        fop[(start_idx >> 4) * LSTR + (start_idx & 15)] = __fmul_rn(WH, h0);
    }
    __syncthreads();

    const float* frow = &fop[lane * LSTR];
    int sel = start_idx;             // first selection is trivially the start cell

    // lane-constant relax geometry
    const int k8 = lane < 8 ? (lane < 4 ? lane : lane + 1) : 4;
    const int di = k8 / 3 - 1;
    const int dj = k8 - (k8 / 3) * 3 - 1;
    const float w = ((di != 0) && (dj != 0)) ? SQRT2F : 1.0f;
    const bool lane8 = (lane < 8);

    #pragma unroll 1
    for (int step = 0; step < NSTEPS; ++step) {
        const bool solved = (sel == goal_idx);
        const int si = sel >> 5, sj = sel & 31;

        // ---- 1. close sel (neighbors never alias sel) ----
        if (lane == 0)
            fop[(sel >> 4) * LSTR + (sel & 15)] = CB;
        asm volatile("" ::: "memory");

        // ---- 2. relax input reads first (they gate the longest dependent chain) ----
        int ni = si + di, nj = sj + dj;
        bool act = lane8 && ((unsigned)ni < 32u) && ((unsigned)nj < 32u);
        int nb = act ? ni * 32 + nj : sel;
        int fa = (nb >> 4) * LSTR + (nb & 15);
        unsigned fbv = __float_as_uint(fop[fa]);   // dummy lanes read sel -> CLOSED -> rel=false
        float gnb = g_s[nb];
        float gsel = g_s[sel];

        // ---- 3. scan loads: AFTER close (sees it), BEFORE relax writes (stale wrt them) ----
        float4 r0 = *(const float4*)(frow + 0);
        float4 r1 = *(const float4*)(frow + 4);
        float4 r2 = *(const float4*)(frow + 8);
        float4 r3 = *(const float4*)(frow + 12);
        asm volatile("" ::: "memory");

        // ---- 4. fh arithmetic (no load; reference-identical op order) ----
        float dxn = fabsf((float)ni - gi);
        float dyn = fabsf((float)nj - gj);
        float hn  = __fadd_rn(__fmul_rn(fminf(dxn, dyn), SQRT2F), fabsf(dxn - dyn));
        float fhn = __fmul_rn(WH, hn);

        // ---- 5. relax compute + writes ----
        float g2 = __fadd_rn(gsel, w);               // exact: fl(g_sel + w)
        bool rel = act && ((fbv == UNVIS) || (fbv < UNVIS && gnb > g2));
        float fnew = __fadd_rn(__fmul_rn(0.5f, g2), fhn);
        if (rel) {
            fop[fa] = fnew;                          // next iter's scan sees this; this iter's doesn't
            g_s[nb] = g2;
            par_s[nb] = (unsigned short)sel;
        }
        if (solved) break;   // relax of the solved step applied (matches reference)

        // ---- 6. value tree (min3) over stale scan + fresh fv, single DPP chain ----
        float fv = rel ? fnew : INFF;                // fresh candidate (strictly < its stale copy)
        float a0 = fminf(fmin3(r0.x, r0.y, r0.z), r0.w);
        float a1 = fminf(fmin3(r1.x, r1.y, r1.z), r1.w);
        float a2 = fminf(fmin3(r2.x, r2.y, r2.z), r2.w);
        float a3 = fminf(fmin3(r3.x, r3.y, r3.z), r3.w);
        float lmin = fminf(fmin3(a0, a1, a2), a3);
        const unsigned lm = __float_as_uint(lmin);
        const float gs = wave_min_f32_bcast(fminf(lmin, fv));   // global min incl fresh
        const unsigned gb = __float_as_uint(gs);

        // slot tree (umin3): independent of DPP chain -> fills its hazard gaps
        unsigned s0 = umin3(umin3(slotc(r0.x, lm, 0),  slotc(r0.y, lm, 1),  slotc(r0.z, lm, 2)),
                            umin3(slotc(r0.w, lm, 3),  slotc(r1.x, lm, 4),  slotc(r1.y, lm, 5)),
                            umin2(slotc(r1.z, lm, 6),  slotc(r1.w, lm, 7)));
        unsigned s1 = umin3(umin3(slotc(r2.x, lm, 8),  slotc(r2.y, lm, 9),  slotc(r2.z, lm, 10)),
                            umin3(slotc(r2.w, lm, 11), slotc(r3.x, lm, 12), slotc(r3.y, lm, 13)),
                            umin2(slotc(r3.z, lm, 14), slotc(r3.w, lm, 15)));
        unsigned slot = umin2(s0, s1);

        // ---- 7. branchless resolve (kills the two uniform s_cbranch bubbles) ----
        const ull bal_s = __ballot(lm == gb);                       // stale matches
        const ull bal_f = __ballot(__float_as_uint(fv) == gb);      // fresh matches (INF never)
        const int owner_s = (int)__builtin_ctzll(bal_s | (1ull << 63));
        const int owner_f = (int)__builtin_ctzll(bal_f | (1ull << 63));
        unsigned raw_s = (unsigned)(owner_s * 16 + __builtin_amdgcn_readlane((int)slot, owner_s));
        unsigned raw_f = (unsigned)__builtin_amdgcn_readlane(nb, owner_f);
        unsigned idx_s = bal_s ? raw_s : 0xFFFFu;   // scalar cselect, no branch
        unsigned idx_f = bal_f ? raw_f : 0xFFFFu;
        sel = (int)umin2(idx_s, idx_f);   // equal values -> lowest flat index (exact tie-break)
    }

    float* out_hist = out + b * SS;
    float* out_path = out + BATCH * SS + b * SS;
    float* out_g    = out + 2 * BATCH * SS + b * SS;
    for (int i = 0; i < 16; ++i) {
        int c = i * 64 + lane;
        unsigned fbv = __float_as_uint(fop[(c >> 4) * LSTR + (c & 15)]);
        out_hist[c] = (fbv == CLOSEDB) ? 1.0f : 0.0f;
        out_g[c]    = g_s[c];
        out_path[c] = (c == goal_idx) ? 1.0f : 0.0f;
    }
    __syncthreads();   // drain stores before backtrack overwrites
    if (lane == 0) {
        int loc = par_s[goal_idx];
        for (int it = 0; it < NSTEPS; ++it) {
            out_path[loc] = 1.0f;
            if (loc == goal_idx) break;   // parent chain strictly decreasing in expansion time
            loc = par_s[loc];
        }
    }
}

extern "C" void kernel_launch(void* const* d_in, const int* in_sizes, int n_in,
                              void* d_out, int out_size, void* d_ws, size_t ws_size,
                              hipStream_t stream)
{
    // d_in: [0]=cost_maps (unused in 'default' mode), [1]=start, [2]=goal, [3]=obstacles
    const float* start_maps = (const float*)d_in[1];
    const float* goal_maps  = (const float*)d_in[2];
    const float* obst_maps  = (const float*)d_in[3];
    float* out = (float*)d_out;
    hipLaunchKernelGGL(astar_kernel, dim3(BATCH), dim3(64), 0, stream,
                       start_maps, goal_maps, obst_maps, out);
}

// Round 18
// 36.096 us; speedup vs baseline: 1.1480x; 1.1480x over previous
//
#include <hip/hip_runtime.h>

#define BATCH 32
#define SS 1024
#define NSTEPS 972
#define LSTR 20                     // floats per lane row: 16 data + 4 pad = 80B (16B-aligned, 8-way bank spread)

#define UNVIS   0x7F000000u         // huge finite float sentinels: UNVIS < CLOSED < OBST, all > any real f
#define CLOSEDB 0x7F000001u
#define OBSTB   0x7F000002u

typedef unsigned long long ull;

template <int CTRL>
__device__ __forceinline__ int dpp32(int v) {
    return __builtin_amdgcn_update_dpp(v, v, CTRL, 0xF, 0xF, false);
}

// 64-lane f32 min, result (bit-exact copy of some input) broadcast via readlane(63).
__device__ __forceinline__ float wave_min_f32_bcast(float v) {
    float t;
    t = __int_as_float(dpp32<0xB1 >(__float_as_int(v))); v = fminf(v, t);  // quad xor1
    t = __int_as_float(dpp32<0x4E >(__float_as_int(v))); v = fminf(v, t);  // quad xor2
    t = __int_as_float(dpp32<0x141>(__float_as_int(v))); v = fminf(v, t);  // row_half_mirror
    t = __int_as_float(dpp32<0x140>(__float_as_int(v))); v = fminf(v, t);  // row_mirror
    t = __int_as_float(dpp32<0x142>(__float_as_int(v))); v = fminf(v, t);  // row_bcast15
    t = __int_as_float(dpp32<0x143>(__float_as_int(v))); v = fminf(v, t);  // row_bcast31
    return __int_as_float(__builtin_amdgcn_readlane(__float_as_int(v), 63));
}

__device__ __forceinline__ unsigned umin2(unsigned a, unsigned b) { return a < b ? a : b; }
__device__ __forceinline__ unsigned slotc(float v, unsigned lm, unsigned i) {
    return (__float_as_uint(v) == lm) ? i : 63u;   // lane-local slot candidate
}

__global__ __launch_bounds__(64)
void astar_kernel(const float* __restrict__ start_maps,
                  const float* __restrict__ goal_maps,
                  const float* __restrict__ obst_maps,
                  float* __restrict__ out)
{
    const int b = blockIdx.x;
    const int lane = threadIdx.x;

    __shared__ __align__(16) float fop[64 * LSTR];   // padded: cell c at (c>>4)*LSTR + (c&15)
    __shared__ __align__(16) float g_s[SS];
    __shared__ unsigned short par_s[SS];
    __shared__ int sh_start, sh_goal;

    const float* st = start_maps + b * SS;
    const float* gl = goal_maps + b * SS;
    const float* ob = obst_maps + b * SS;

    for (int i = 0; i < 16; ++i) {
        int c = i * 64 + lane;
        if (st[c] > 0.5f) sh_start = c;
        if (gl[c] > 0.5f) sh_goal = c;
    }
    __syncthreads();
    const int start_idx = sh_start;
    const int goal_idx = sh_goal;
    const float gi = (float)(goal_idx >> 5);
    const float gj = (float)(goal_idx & 31);
    const float SQRT2F = 1.41421356237309515f;   // fl32(sqrt(2))
    const float WH = 0.501f;
    const float INFF = __int_as_float(0x7f800000);
    const float CB = __uint_as_float(CLOSEDB);

    for (int i = 0; i < 16; ++i) {
        int c = i * 64 + lane;
        g_s[c] = 0.0f;
        par_s[c] = (unsigned short)goal_idx;
        fop[(c >> 4) * LSTR + (c & 15)] = __uint_as_float(ob[c] > 0.5f ? UNVIS : OBSTB);
    }
    __syncthreads();
    if (lane == 0) {
        // f(start) = fl(0.5*0 + fl(0.501*h)) = fh, computed with init-identical op order
        float dx0 = fabsf((float)(start_idx >> 5) - gi);
        float dy0 = fabsf((float)(start_idx & 31) - gj);
        float h0 = __fadd_rn(__fmul_rn(fminf(dx0, dy0), SQRT2F), fabsf(dx0 - dy0));
        fop[(start_idx >> 4) * LSTR + (start_idx & 15)] = __fmul_rn(WH, h0);
    }
    __syncthreads();

    const float* frow = &fop[lane * LSTR];
    int sel = start_idx;             // first selection is trivially the start cell

    #pragma unroll 1
    for (int step = 0; step < NSTEPS; ++step) {
        const bool solved = (sel == goal_idx);
        const int si = sel >> 5, sj = sel & 31;

        // ---- 1. close sel (neighbors never alias sel) ----
        if (lane == 0)
            fop[(sel >> 4) * LSTR + (sel & 15)] = CB;
        asm volatile("" ::: "memory");

        // ---- 2. relax input reads (issued FIRST -> counted wait covers them early) ----
        int k8 = lane < 8 ? (lane < 4 ? lane : lane + 1) : 4;
        int di = k8 / 3 - 1;
        int dj = k8 - (k8 / 3) * 3 - 1;
        int ni = si + di, nj = sj + dj;
        bool act = (lane < 8) && ((unsigned)ni < 32u) && ((unsigned)nj < 32u);
        int nb = act ? ni * 32 + nj : sel;
        int fa = (nb >> 4) * LSTR + (nb & 15);
        unsigned fbv = __float_as_uint(fop[fa]);   // dummy lanes read sel -> CLOSED -> rel=false
        float gnb = g_s[nb];
        float gsel = g_s[sel];

        // ---- 3. scan loads: AFTER close (sees it), BEFORE relax writes (stale wrt them) ----
        float4 r0 = *(const float4*)(frow + 0);
        float4 r1 = *(const float4*)(frow + 4);
        float4 r2 = *(const float4*)(frow + 8);
        float4 r3 = *(const float4*)(frow + 12);
        asm volatile("" ::: "memory");

        // ---- 4. fh arithmetic (no load; bit-identical op order to reference) ----
        float dxn = fabsf((float)ni - gi);
        float dyn = fabsf((float)nj - gj);
        float hn  = __fadd_rn(__fmul_rn(fminf(dxn, dyn), SQRT2F), fabsf(dxn - dyn));
        float fhn = __fmul_rn(WH, hn);

        // ---- 5. relax compute + writes (scan loads above are NOT drained by this wait) ----
        float w = ((di != 0) && (dj != 0)) ? SQRT2F : 1.0f;
        float g2 = __fadd_rn(gsel, w);               // exact: fl(g_sel + w)
        bool rel = act && ((fbv == UNVIS) || (fbv < UNVIS && gnb > g2));
        float fnew = __fadd_rn(__fmul_rn(0.5f, g2), fhn);
        if (rel) {
            fop[fa] = fnew;                          // next iter's scan sees this; this iter's doesn't
            g_s[nb] = g2;
            par_s[nb] = (unsigned short)sel;
        }
        if (solved) break;   // relax of the solved step applied (matches reference); tree skipped

        // ---- 6. tree over stale scan + fresh keys merged in-resolve ----
        float fv = rel ? fnew : INFF;                // fresh candidate (strictly < its stale copy)
        float a0 = fminf(fminf(r0.x, r0.y), fminf(r0.z, r0.w));
        float a1 = fminf(fminf(r1.x, r1.y), fminf(r1.z, r1.w));
        float a2 = fminf(fminf(r2.x, r2.y), fminf(r2.z, r2.w));
        float a3 = fminf(fminf(r3.x, r3.y), fminf(r3.z, r3.w));
        float lmin = fminf(fminf(a0, a1), fminf(a2, a3));
        const unsigned lm = __float_as_uint(lmin);
        unsigned s0 = umin2(umin2(slotc(r0.x, lm, 0),  slotc(r0.y, lm, 1)),
                            umin2(slotc(r0.z, lm, 2),  slotc(r0.w, lm, 3)));
        unsigned s1 = umin2(umin2(slotc(r1.x, lm, 4),  slotc(r1.y, lm, 5)),
                            umin2(slotc(r1.z, lm, 6),  slotc(r1.w, lm, 7)));
        unsigned s2 = umin2(umin2(slotc(r2.x, lm, 8),  slotc(r2.y, lm, 9)),
                            umin2(slotc(r2.z, lm, 10), slotc(r2.w, lm, 11)));
        unsigned s3 = umin2(umin2(slotc(r3.x, lm, 12), slotc(r3.y, lm, 13)),
                            umin2(slotc(r3.z, lm, 14), slotc(r3.w, lm, 15)));
        unsigned slot = umin2(umin2(s0, s1), umin2(s2, s3));

        const float gmin = wave_min_f32_bcast(fminf(lmin, fv));
        const unsigned gb = __float_as_uint(gmin);
        const ull bal_s = __ballot(lm == gb);                       // stale matches
        const ull bal_f = __ballot(__float_as_uint(fv) == gb);      // fresh matches (INF never matches)

        unsigned idx_s = 0xFFFFu, idx_f = 0xFFFFu;
        if (bal_s) {            // uniform branch (SGPR)
            int owner = (int)__builtin_ctzll(bal_s);                // lowest lane = lowest cell block
            idx_s = (unsigned)(owner * 16 + __builtin_amdgcn_readlane((int)slot, owner));
        }
        if (bal_f) {            // fresh lanes are nb-ascending -> ctz = lowest fresh cell
            int fl = (int)__builtin_ctzll(bal_f);
            idx_f = (unsigned)__builtin_amdgcn_readlane(nb, fl);
        }
        sel = (int)umin2(idx_s, idx_f);   // equal values -> lowest flat index (exact tie-break)
    }

    float* out_hist = out + b * SS;
    float* out_path = out + BATCH * SS + b * SS;
    float* out_g    = out + 2 * BATCH * SS + b * SS;
    for (int i = 0; i < 16; ++i) {
        int c = i * 64 + lane;
        unsigned fbv = __float_as_uint(fop[(c >> 4) * LSTR + (c & 15)]);
        out_hist[c] = (fbv == CLOSEDB) ? 1.0f : 0.0f;
        out_g[c]    = g_s[c];
        out_path[c] = (c == goal_idx) ? 1.0f : 0.0f;
    }
    __syncthreads();   // drain stores before backtrack overwrites
    if (lane == 0) {
        int loc = par_s[goal_idx];
        for (int it = 0; it < NSTEPS; ++it) {
            out_path[loc] = 1.0f;
            if (loc == goal_idx) break;   // parent chain strictly decreasing in expansion time
            loc = par_s[loc];
        }
    }
}

extern "C" void kernel_launch(void* const* d_in, const int* in_sizes, int n_in,
                              void* d_out, int out_size, void* d_ws, size_t ws_size,
                              hipStream_t stream)
{
    // d_in: [0]=cost_maps (unused in 'default' mode), [1]=start, [2]=goal, [3]=obstacles
    const float* start_maps = (const float*)d_in[1];
    const float* goal_maps  = (const float*)d_in[2];
    const float* obst_maps  = (const float*)d_in[3];
    float* out = (float*)d_out;
    hipLaunchKernelGGL(astar_kernel, dim3(BATCH), dim3(64), 0, stream,
                       start_maps, goal_maps, obst_maps, out);
}